// Round 1
// baseline (545.764 us; speedup 1.0000x reference)
//
#include <hip/hip_runtime.h>

#define NROWS 131072
#define KDIM 512
#define NDIM 512

using short8  = __attribute__((ext_vector_type(8))) short;
using float4v = __attribute__((ext_vector_type(4))) float;
using uint4v  = __attribute__((ext_vector_type(4))) unsigned int;

// pack two fp32 -> bf16x2 (truncation; 1 v_perm per pair)
__device__ __forceinline__ unsigned pack_trunc(float a, float b) {
    unsigned ua = __builtin_bit_cast(unsigned, a);
    unsigned ub = __builtin_bit_cast(unsigned, b);
    return __builtin_amdgcn_perm(ub, ua, 0x07060302u);
}
// pack two fp32 -> bf16x2 (round-half-up on magnitude; off hot path)
__device__ __forceinline__ unsigned pack_round(float a, float b) {
    unsigned ua = __builtin_bit_cast(unsigned, a) + 0x8000u;
    unsigned ub = __builtin_bit_cast(unsigned, b) + 0x8000u;
    return __builtin_amdgcn_perm(ub, ua, 0x07060302u);
}

// Pass 1: W [8][512 in][512 out] fp32  ->  Wt [8][512 out][512 in] bf16
__global__ __launch_bounds__(256) void wconv_kernel(const float* __restrict__ w,
                                                    unsigned short* __restrict__ wt) {
    int b  = blockIdx.x;          // 512 blocks
    int ty = b >> 6;              // type 0..7
    int ot = (b >> 3) & 7;        // out-tile of 64
    int it = b & 7;               // in-tile of 64
    __shared__ float tile[64][65];
    const float* wp = w + ((size_t)ty << 18);
    int tid = threadIdx.x;
    // load 64(in) x 64(out), coalesced along out
    int cf = tid & 15, ir0 = tid >> 4;
    #pragma unroll
    for (int j = 0; j < 4; ++j) {
        int ir = ir0 + 16 * j;
        float4v v = *(const float4v*)(wp + (size_t)(it * 64 + ir) * NDIM + ot * 64 + cf * 4);
        tile[ir][cf * 4 + 0] = v.x;
        tile[ir][cf * 4 + 1] = v.y;
        tile[ir][cf * 4 + 2] = v.z;
        tile[ir][cf * 4 + 3] = v.w;
    }
    __syncthreads();
    // write transposed bf16, coalesced-ish along in
    int oc = tid >> 2, iq = tid & 3;
    unsigned* op = (unsigned*)(wt + ((size_t)ty << 18) + (size_t)(ot * 64 + oc) * KDIM + it * 64 + iq * 16);
    #pragma unroll
    for (int j = 0; j < 8; ++j)
        op[j] = pack_round(tile[iq * 16 + 2 * j][oc], tile[iq * 16 + 2 * j + 1][oc]);
}

// Pass 2: out[128x128 tile] = bf16(x) @ Wt[t] + bias[t], per-row t, sorted.
__global__ __launch_bounds__(256, 2)
void hetero_gemm_kernel(const float* __restrict__ x,
                        const int* __restrict__ tv,
                        const unsigned short* __restrict__ wt,
                        const float* __restrict__ bias,
                        float* __restrict__ out) {
    __shared__ uint4v ldsA[4 * 128];   // [kgrp][row] 16B units (8 bf16, k-contig)
    __shared__ uint4v ldsB[4 * 128];   // [kgrp][col]

    const int b = blockIdx.x;
    // swizzle: 4 col-tiles of a row-tile share b%8 (same XCD heuristic)
    const int rowTile = ((b >> 5) << 3) | (b & 7);
    const int colTile = (b >> 3) & 3;
    const int row0 = rowTile << 7;
    const int col0 = colTile << 7;

    const int tid  = threadIdx.x;
    const int lane = tid & 63;
    const int wave = tid >> 6;
    const int wm   = (wave & 1) << 6;   // 0 / 64
    const int wn   = (wave >> 1) << 6;  // 0 / 64
    const int l15  = lane & 15;
    const int quad = lane >> 4;

    // A staging: thread -> (row ra, k-half khalf)  (16 fp32 each)
    const int ra = tid >> 1;
    const int khalf = tid & 1;
    const int rtypeA = tv[row0 + ra];

    // B staging: thread -> (col nb, kgrp pair g2)  (2x 16B bf16 units)
    const int nb = tid & 127;
    const int g2 = tid >> 7;

    const int t0 = tv[row0];
    const int t1 = tv[row0 + 127];

    float4v acc[4][4];
    float4v zero = {0.f, 0.f, 0.f, 0.f};
    #pragma unroll
    for (int i = 0; i < 4; ++i)
        #pragma unroll
        for (int j = 0; j < 4; ++j)
            acc[i][j] = zero;

    for (int tt = t0; tt <= t1; ++tt) {
        const unsigned maskA = (rtypeA == tt) ? 0xFFFFFFFFu : 0u;
        const float* ap = x + (size_t)(row0 + ra) * KDIM + khalf * 16;
        const unsigned short* wb = wt + ((size_t)tt << 18) + (size_t)(col0 + nb) * KDIM;

        float4v av[4];
        uint4v  bv[2];
        #pragma unroll
        for (int i = 0; i < 4; ++i) av[i] = *(const float4v*)(ap + i * 4);
        bv[0] = *(const uint4v*)(wb + g2 * 8);
        bv[1] = *(const uint4v*)(wb + (g2 + 2) * 8);

        for (int kc = 0; kc < KDIM; kc += 32) {
            __syncthreads();
            uint4v pa0, pa1;
            pa0.x = pack_trunc(av[0].x, av[0].y) & maskA;
            pa0.y = pack_trunc(av[0].z, av[0].w) & maskA;
            pa0.z = pack_trunc(av[1].x, av[1].y) & maskA;
            pa0.w = pack_trunc(av[1].z, av[1].w) & maskA;
            pa1.x = pack_trunc(av[2].x, av[2].y) & maskA;
            pa1.y = pack_trunc(av[2].z, av[2].w) & maskA;
            pa1.z = pack_trunc(av[3].x, av[3].y) & maskA;
            pa1.w = pack_trunc(av[3].z, av[3].w) & maskA;
            ldsA[(khalf * 2 + 0) * 128 + ra] = pa0;
            ldsA[(khalf * 2 + 1) * 128 + ra] = pa1;
            ldsB[(g2    ) * 128 + nb] = bv[0];
            ldsB[(g2 + 2) * 128 + nb] = bv[1];
            __syncthreads();

            // register prefetch of next chunk overlaps with MFMA below
            if (kc + 32 < KDIM) {
                const float* ap2 = ap + kc + 32;
                #pragma unroll
                for (int i = 0; i < 4; ++i) av[i] = *(const float4v*)(ap2 + i * 4);
                const unsigned short* wb2 = wb + kc + 32;
                bv[0] = *(const uint4v*)(wb2 + g2 * 8);
                bv[1] = *(const uint4v*)(wb2 + (g2 + 2) * 8);
            }

            short8 af[4], bf[4];
            #pragma unroll
            for (int mi = 0; mi < 4; ++mi)
                af[mi] = *(const short8*)&ldsA[quad * 128 + wm + mi * 16 + l15];
            #pragma unroll
            for (int ni = 0; ni < 4; ++ni)
                bf[ni] = *(const short8*)&ldsB[quad * 128 + wn + ni * 16 + l15];
            #pragma unroll
            for (int mi = 0; mi < 4; ++mi)
                #pragma unroll
                for (int ni = 0; ni < 4; ++ni)
                    acc[mi][ni] = __builtin_amdgcn_mfma_f32_16x16x32_bf16(
                        af[mi], bf[ni], acc[mi][ni], 0, 0, 0);
        }
    }

    // epilogue: D row = quad*4+reg, col = lane&15 (m89-verified layout)
    #pragma unroll
    for (int mi = 0; mi < 4; ++mi) {
        #pragma unroll
        for (int r = 0; r < 4; ++r) {
            const int grow = row0 + wm + mi * 16 + quad * 4 + r;
            const int rt = tv[grow];
            const float* brow = bias + (size_t)rt * NDIM;
            float* orow = out + (size_t)grow * NDIM;
            #pragma unroll
            for (int ni = 0; ni < 4; ++ni) {
                const int gcol = col0 + wn + ni * 16 + l15;
                orow[gcol] = acc[mi][ni][r] + brow[gcol];
            }
        }
    }
}

extern "C" void kernel_launch(void* const* d_in, const int* in_sizes, int n_in,
                              void* d_out, int out_size, void* d_ws, size_t ws_size,
                              hipStream_t stream) {
    const float* x    = (const float*)d_in[0];
    const int*   tv   = (const int*)d_in[1];
    const float* w    = (const float*)d_in[2];
    const float* bias = (const float*)d_in[3];
    float* out = (float*)d_out;
    unsigned short* wtr = (unsigned short*)d_ws;   // 8*512*512*2 = 4 MiB

    wconv_kernel<<<512, 256, 0, stream>>>(w, wtr);
    hetero_gemm_kernel<<<4096, 256, 0, stream>>>(x, tv, wtr, bias, out);
}